// Round 1
// 890.267 us; speedup vs baseline: 1.3458x; 1.3458x over previous
//
#include <hip/hip_runtime.h>
#include <cstdint>
#include <cstddef>

// ---------------- constants ----------------
#define N_TOK   16384      // 4 * 4096
#define D_TOTAL 2048
#define N_HEAD  16
#define D_HEAD  128
#define HID     512
#define MT      64         // tokens per block in fused kernel
#define RMS_EPS 1.1920929e-07f   // np.finfo(np.float32).eps

typedef __attribute__((ext_vector_type(8))) short  short8;
typedef __attribute__((ext_vector_type(4))) float  float4_t;
typedef __attribute__((ext_vector_type(2))) unsigned int uint2_t;

// ---------------- bf16 helpers ----------------
__device__ __forceinline__ unsigned short f2bf(float f) {
    union { float f; unsigned int i; } v; v.f = f;
    unsigned int b = v.i;
    b += 0x7FFFu + ((b >> 16) & 1u);      // round-to-nearest-even
    return (unsigned short)(b >> 16);
}

// packed fp32x2 -> bf16x2 (RNE, same rounding as f2bf); no builtin on gfx950
__device__ __forceinline__ unsigned int cvt_pk_bf16(float lo, float hi) {
    unsigned int r;
    asm("v_cvt_pk_bf16_f32 %0, %1, %2" : "=v"(r) : "v"(lo), "v"(hi));
    return r;
}

// Exact-GELU via Abramowitz-Stegun 7.1.26 erf (|eps| <= 1.5e-7), branchless.
// gelu(x) = 0.5x(1+erf(x/sqrt2)) = 0.5x + 0.5|x|*erf(|x|/sqrt2)  (sign-free)
__device__ __forceinline__ float gelu_exact(float x) {
    float ax = fabsf(x);
    // t = 1/(1 + 0.3275911*|x|/sqrt2) = 1/(1 + 0.23164193*|x|)
    float t  = __builtin_amdgcn_rcpf(fmaf(0.23164193f, ax, 1.0f));
    float poly = fmaf(fmaf(fmaf(fmaf(1.061405429f, t, -1.453152027f),
                               t, 1.421413741f), t, -0.284496736f),
                      t, 0.254829592f) * t;
    // exp(-z^2) = exp2(-x^2 * 0.5 * log2(e)) = exp2(x^2 * -0.72134752)
    float e    = exp2f(x * x * -0.72134752f);
    float erfa = fmaf(-poly, e, 1.0f);          // erf(|z|)
    return fmaf(0.5f * ax, erfa, 0.5f * x);
}

// ---------------- kernel 1: per-token inv-RMS (fp32 input) ----------------
__global__ __launch_bounds__(256) void rms_scale_kernel(
    const float* __restrict__ x, float* __restrict__ scale)
{
    const int lane  = threadIdx.x & 63;
    const int wv    = threadIdx.x >> 6;
    const int token = blockIdx.x * 4 + wv;

    const float* xp = x + (size_t)token * D_TOTAL;
    float s = 0.0f;
#pragma unroll
    for (int j = 0; j < 8; ++j) {
        float4 v = *(const float4*)(xp + (size_t)(j * 64 + lane) * 4);
        s += v.x * v.x + v.y * v.y + v.z * v.z + v.w * v.w;
    }
#pragma unroll
    for (int off = 32; off > 0; off >>= 1) s += __shfl_down(s, off, 64);
    if (lane == 0)
        scale[token] = rsqrtf(s * (1.0f / (float)D_TOTAL) + RMS_EPS);
}

// -------- kernel 2: weight transpose+cast  W[h][K][N] (fp32) -> WT[h][N][K] (bf16)
// Optional gmul: per-(h,k) multiplier (folds RMSNorm weight g into w0).
__global__ __launch_bounds__(256) void transpose_kernel(
    const float* __restrict__ in, unsigned short* __restrict__ out, int K, int N,
    const float* __restrict__ gmul)
{
    const int ktiles = K >> 6, ntiles = N >> 6;
    const int b   = blockIdx.x;
    const int h   = b / (ktiles * ntiles);
    const int rem = b % (ktiles * ntiles);
    const int kt  = rem / ntiles, nt = rem % ntiles;

    const float* src = in + (size_t)h * K * N + (size_t)(kt * 64) * N + nt * 64;
    unsigned short* dst = out + (size_t)h * N * K + (size_t)(nt * 64) * K + kt * 64;

    __shared__ unsigned short tile[64][72];

#pragma unroll
    for (int p = 0; p < 2; ++p) {
        int gi = threadIdx.x + p * 256;
        int r  = gi >> 3;                 // row within tile = k offset
        int gc = (gi & 7) * 8;
        float mul = 1.0f;
        if (gmul) mul = gmul[(size_t)h * K + kt * 64 + r];
        float4 a  = *(const float4*)(src + (size_t)r * N + gc);
        float4 b4 = *(const float4*)(src + (size_t)r * N + gc + 4);
        unsigned short tmp[8];
        tmp[0]=f2bf(a.x*mul);  tmp[1]=f2bf(a.y*mul);  tmp[2]=f2bf(a.z*mul);  tmp[3]=f2bf(a.w*mul);
        tmp[4]=f2bf(b4.x*mul); tmp[5]=f2bf(b4.y*mul); tmp[6]=f2bf(b4.z*mul); tmp[7]=f2bf(b4.w*mul);
        *(uint4*)&tile[r][gc] = *(const uint4*)tmp;
    }
    __syncthreads();
#pragma unroll
    for (int p = 0; p < 2; ++p) {
        int gi  = threadIdx.x + p * 256;
        int r2  = gi >> 3;
        int gc2 = (gi & 7) * 8;
        unsigned short tmp[8];
#pragma unroll
        for (int j = 0; j < 8; ++j) tmp[j] = tile[gc2 + j][r2];
        *(uint4*)(dst + (size_t)r2 * K + gc2) = *(const uint4*)tmp;
    }
}

// ---------------- fused chain GEMM stage (operand-swapped) ----------------
// Computes Y^T tiles: D = mfma(A = W^T frag, B = X^T frag).
//   A (weights):    lane holds row n = nbase+nt*16+(lane&15), 8 k-contig at (lane>>4)*8
//   B (activations):lane holds col tok = mt*16+(lane&15),     8 k-contig at (lane>>4)*8
//   D: col = token (lane&15), row = n ((lane>>4)*4 + reg)  -> 4 consecutive n per lane!
// K-loop fully unrolled: immediate-offset global loads, base^(ks*64) LDS addressing.
template<int K, int NT>
__device__ __forceinline__ void stage_gemm(
    const unsigned short* __restrict__ sA,      // LDS, 64 x 512 bf16, XOR-swizzled
    const unsigned short* __restrict__ wt,      // global bf16, [N][K] this head
    int lane, int nbase, float4_t acc[4][NT])
{
#pragma unroll
    for (int mt = 0; mt < 4; ++mt)
#pragma unroll
        for (int nt = 0; nt < NT; ++nt) {
            float4_t z = {0.0f, 0.0f, 0.0f, 0.0f};
            acc[mt][nt] = z;
        }

    const int r15 = lane & 15;
    const int q   = lane >> 4;

    // A (weight) row base pointers: n fixed across the K loop
    const char* arow[NT];
#pragma unroll
    for (int nt = 0; nt < NT; ++nt)
        arow[nt] = (const char*)(wt + (size_t)(nbase + nt * 16 + r15) * K + q * 8);

    // B (activation) swizzled byte-address bases: addr(ks) = vb ^ (ks*64)
    // elem addr = row*512 + (( (ks*4+q) ^ (row&7) )*8); row = mt*16 + r15
    const char* sab = (const char*)sA;
    unsigned int vb[4];
    const unsigned int hb = ((unsigned)(r15 >> 2) & 1u) << 6;
#pragma unroll
    for (int mt = 0; mt < 4; ++mt) {
        unsigned int row = (unsigned)(mt * 16 + r15);
        vb[mt] = row * 1024u + (((unsigned)(q ^ (r15 & 3))) << 4) + hb;
    }

#pragma unroll
    for (int ks = 0; ks < K / 32; ++ks) {
        short8 a[NT], b[4];
#pragma unroll
        for (int nt = 0; nt < NT; ++nt)
            a[nt] = *(const short8*)(arow[nt] + ks * 64);
#pragma unroll
        for (int mt = 0; mt < 4; ++mt)
            b[mt] = *(const short8*)(sab + (vb[mt] ^ (unsigned)(ks * 64)));
#pragma unroll
        for (int mt = 0; mt < 4; ++mt)
#pragma unroll
            for (int nt = 0; nt < NT; ++nt)
                acc[mt][nt] = __builtin_amdgcn_mfma_f32_16x16x32_bf16(
                    a[nt], b[mt], acc[mt][nt], 0, 0, 0);
    }
}

// gelu + pack + swizzled LDS writeback.
// Swapped D layout: lane holds 4 consecutive n (q*4+r) for token mt*16+(lane&15)
// -> 2x cvt_pk + one 8-byte LDS write per (mt,nt). 8B write stays inside one
//    16B swizzle granule (q*4 & 7 is 0 or 4).
template<int NT>
__device__ __forceinline__ void epi_gelu(
    unsigned short* __restrict__ sAct, int lane, int nbase, float4_t acc[4][NT])
{
    const int q  = lane >> 4;
    const int c0 = lane & 15;
#pragma unroll
    for (int mt = 0; mt < 4; ++mt) {
        const int tok   = mt * 16 + c0;
        const unsigned int rbase = (unsigned)tok * HID;
        const int tk7   = tok & 7;
#pragma unroll
        for (int nt = 0; nt < NT; ++nt) {
            const int col = nbase + nt * 16 + q * 4;
            float g0 = gelu_exact(acc[mt][nt][0]);
            float g1 = gelu_exact(acc[mt][nt][1]);
            float g2 = gelu_exact(acc[mt][nt][2]);
            float g3 = gelu_exact(acc[mt][nt][3]);
            uint2_t v;
            v.x = cvt_pk_bf16(g0, g1);
            v.y = cvt_pk_bf16(g2, g3);
            const int gsw = (col >> 3) ^ tk7;
            *(uint2_t*)&sAct[rbase + gsw * 8 + (col & 7)] = v;
        }
    }
}

// ---------------- kernel 3: fused per-(head, token-tile) chain ----------------
// XCD-aware decode: blocks land on XCD (bx & 7); pin each XCD to 2 heads,
// grouped in time -> concurrent weight working set per XCD = 1.25 MB < 4 MB L2.
__global__ __launch_bounds__(256, 2) void fused_chain_kernel(
    const float*          __restrict__ x,     // fp32
    const float*          __restrict__ scale,
    const unsigned short* __restrict__ wt0,   // [H][512][128] bf16 (g pre-folded)
    const unsigned short* __restrict__ wt1,   // [H][512][512] bf16
    const unsigned short* __restrict__ wt2,   // [H][512][512] bf16
    const unsigned short* __restrict__ wt3,   // [H][128][512] bf16
    float*                __restrict__ out)   // fp32
{
    __shared__ unsigned short sAct[MT * HID];   // 64 KiB

    const int tid  = threadIdx.x;
    const int lane = tid & 63;
    const int wv   = tid >> 6;
    const int bx    = blockIdx.x;
    const int xcd   = bx & 7;
    const int local = bx >> 3;            // 0..511
    const int head  = xcd * 2 + (local >> 8);
    const int tile  = local & 255;
    const int tok0  = tile * MT;

    // ---- stage 0: normalized x-slice (bf16) into cols [0,128) of sAct ----
    // (g is folded into wt0 at transpose time)
#pragma unroll
    for (int p = 0; p < 4; ++p) {
        int gi = tid + p * 256;          // 0..1023 granules (64 rows x 16)
        int r  = gi >> 4;
        int gc = gi & 15;
        int token = tok0 + r;
        const float* xp = x + (size_t)token * D_TOTAL + head * D_HEAD + gc * 8;
        float4 xa = *(const float4*)(xp);
        float4 xb = *(const float4*)(xp + 4);
        float s = scale[token];
        unsigned int u[4];
        u[0] = cvt_pk_bf16(xa.x * s, xa.y * s);
        u[1] = cvt_pk_bf16(xa.z * s, xa.w * s);
        u[2] = cvt_pk_bf16(xb.x * s, xb.y * s);
        u[3] = cvt_pk_bf16(xb.z * s, xb.w * s);
        int gsw = gc ^ (r & 7);
        *(uint4*)&sAct[r * HID + gsw * 8] = *(const uint4*)u;
    }
    __syncthreads();

    float4_t acc[4][8];
    const int nb = wv * 128;             // this wave's N-chunk for stages 1-3

    // ---- stage 1: K=128 -> N=512 ----
    stage_gemm<128, 8>(sAct, wt0 + (size_t)head * HID * D_HEAD, lane, nb, acc);
    __syncthreads();
    epi_gelu<8>(sAct, lane, nb, acc);
    __syncthreads();

    // ---- stage 2: K=512 -> N=512 ----
    stage_gemm<512, 8>(sAct, wt1 + (size_t)head * HID * HID, lane, nb, acc);
    __syncthreads();
    epi_gelu<8>(sAct, lane, nb, acc);
    __syncthreads();

    // ---- stage 3: K=512 -> N=512 ----
    stage_gemm<512, 8>(sAct, wt2 + (size_t)head * HID * HID, lane, nb, acc);
    __syncthreads();
    epi_gelu<8>(sAct, lane, nb, acc);
    __syncthreads();

    // ---- stage 4: K=512 -> N=128, straight to global fp32 (no gelu) ----
    float4_t acc2[4][2];
    stage_gemm<512, 2>(sAct, wt3 + (size_t)head * D_HEAD * HID, lane, wv * 32, acc2);

    // Swapped D: lane holds 4 consecutive output cols for a fixed token
    // -> one global_store_dwordx4 per (mt,nt); 4 lanes/token fill a 64B run.
    const int q  = lane >> 4;
    const int c0 = lane & 15;
#pragma unroll
    for (int mt = 0; mt < 4; ++mt) {
        const int token = tok0 + mt * 16 + c0;
#pragma unroll
        for (int nt = 0; nt < 2; ++nt) {
            const int col = head * D_HEAD + wv * 32 + nt * 16 + q * 4;
            *(float4_t*)&out[(size_t)token * D_TOTAL + col] = acc2[mt][nt];
        }
    }
}

// ---------------- host launcher ----------------
extern "C" void kernel_launch(void* const* d_in, const int* in_sizes, int n_in,
                              void* d_out, int out_size, void* d_ws, size_t ws_size,
                              hipStream_t stream)
{
    const float* x  = (const float*)d_in[0];
    const float* gw = (const float*)d_in[1];
    const float* w0 = (const float*)d_in[2];
    const float* w1 = (const float*)d_in[3];
    const float* w2 = (const float*)d_in[4];
    const float* w3 = (const float*)d_in[5];
    float* out = (float*)d_out;

    // workspace layout
    float* scale = (float*)d_ws;                                   // 64 KB
    unsigned short* wt0 = (unsigned short*)((char*)d_ws + 65536);  // [16][512][128]
    unsigned short* wt1 = wt0 + (size_t)N_HEAD * HID * D_HEAD;     // [16][512][512]
    unsigned short* wt2 = wt1 + (size_t)N_HEAD * HID * HID;        // [16][512][512]
    unsigned short* wt3 = wt2 + (size_t)N_HEAD * HID * HID;        // [16][128][512]

    rms_scale_kernel<<<N_TOK / 4, 256, 0, stream>>>(x, scale);

    // g folded into w0 rows (h_norm * g) @ w0 == (x*s) @ (diag(g) w0)
    transpose_kernel<<<N_HEAD * (D_HEAD/64) * (HID/64), 256, 0, stream>>>(w0, wt0, D_HEAD, HID, gw);
    transpose_kernel<<<N_HEAD * (HID/64)    * (HID/64), 256, 0, stream>>>(w1, wt1, HID,    HID, nullptr);
    transpose_kernel<<<N_HEAD * (HID/64)    * (HID/64), 256, 0, stream>>>(w2, wt2, HID,    HID, nullptr);
    transpose_kernel<<<N_HEAD * (HID/64)    * (D_HEAD/64), 256, 0, stream>>>(w3, wt3, HID, D_HEAD, nullptr);

    fused_chain_kernel<<<N_HEAD * (N_TOK / MT), 256, 0, stream>>>(
        x, scale, wt0, wt1, wt2, wt3, out);
}